// Round 2
// baseline (466.369 us; speedup 1.0000x reference)
//
#include <hip/hip_runtime.h>

typedef __bf16 bf16x8 __attribute__((ext_vector_type(8)));
typedef float  f32x4  __attribute__((ext_vector_type(4)));
typedef unsigned int u32x4 __attribute__((ext_vector_type(4)));

#define B_   2
#define N_   512
#define ND_  256
#define ED_  64
#define NH_  8
#define DH_  32

static __device__ __forceinline__ unsigned pack_bf16(float a, float b) {
    unsigned short ua = __builtin_bit_cast(unsigned short, (__bf16)a);
    unsigned short ub = __builtin_bit_cast(unsigned short, (__bf16)b);
    return (unsigned)ua | ((unsigned)ub << 16);
}

// ---------------- prep kernel 1: edge-weight fp32 -> bf16 (row-major [256][64])
__global__ __launch_bounds__(256) void cvt_w_kernel(
    const float* __restrict__ wq, const float* __restrict__ wk,
    const float* __restrict__ wv, unsigned short* __restrict__ w16)
{
    int id = blockIdx.x * 256 + threadIdx.x;          // 0..49151
    const float* src = (id < 16384) ? wq : (id < 32768 ? wk : wv);
    int idx = id & 16383;
    w16[id] = __builtin_bit_cast(unsigned short, (__bf16)src[idx]);
}

// ---------------- prep kernel 1b: transpose node weights -> Wt[m][k][c] fp32
__global__ __launch_bounds__(256) void trans_w_kernel(
    const float* __restrict__ Wq, const float* __restrict__ Wk,
    const float* __restrict__ Wv, float* __restrict__ Wt)
{
    __shared__ float t[32][33];
    const int bx = blockIdx.x;        // 0..191 = 3 mats * 64 tiles
    const int m  = bx >> 6;
    const int t6 = bx & 63;
    const int cb = (t6 >> 3) << 5;    // c-block
    const int kb = (t6 & 7) << 5;     // k-block
    const float* W = (m == 0) ? Wq : (m == 1 ? Wk : Wv);
    const int tx = threadIdx.x & 31, ty = threadIdx.x >> 5;   // 32 x 8
    #pragma unroll
    for (int s = 0; s < 4; s++)
        t[ty + 8 * s][tx] = W[(size_t)(cb + ty + 8 * s) * ND_ + kb + tx];
    __syncthreads();
    float* dst = Wt + (size_t)m * ND_ * ND_;
    #pragma unroll
    for (int s = 0; s < 4; s++)
        dst[(size_t)(kb + ty + 8 * s) * ND_ + cb + tx] = t[tx][ty + 8 * s];
}

// ------- prep kernel 2: node projections with coalesced (transposed) weights.
// Q -> row-major head-split Qh[bh][i][32].
// K,V -> KVp in MFMA C-fragment order so attn loads are lane-linear:
//   KVp float idx = ((bh*32 + j/16)*4 + set)*256 + (((d>>2)&3)*16 + (j&15))*4 + (d&3)
//   set: 0,1 = K halves (d<16 / d>=16), 2,3 = V halves.
__global__ __launch_bounds__(256) void qkv_kernel(
    const float* __restrict__ node, const float* __restrict__ Wt,
    const float* __restrict__ bnq, const float* __restrict__ bnk,
    const float* __restrict__ bnv, const float* __restrict__ beq,
    const float* __restrict__ bek, const float* __restrict__ bev,
    float* __restrict__ Qh, float* __restrict__ KVp)
{
    __shared__ float xs[4][ND_];
    const int c   = threadIdx.x;
    const int m   = blockIdx.x >> 8;       // 0=Q 1=K 2=V
    const int grp = blockIdx.x & 255;
    const int g0  = grp * 4;
    {
        const int r = c >> 6, col4 = (c & 63) * 4;
        const float4 v = *reinterpret_cast<const float4*>(node + (size_t)(g0 + r) * ND_ + col4);
        *reinterpret_cast<float4*>(&xs[r][col4]) = v;
    }
    __syncthreads();

    const float* Wm = Wt + (size_t)m * ND_ * ND_;
    float acc[4] = {0.f, 0.f, 0.f, 0.f};
    for (int k = 0; k < ND_; k += 4) {
        const float w0 = Wm[(size_t)(k + 0) * ND_ + c];
        const float w1 = Wm[(size_t)(k + 1) * ND_ + c];
        const float w2 = Wm[(size_t)(k + 2) * ND_ + c];
        const float w3 = Wm[(size_t)(k + 3) * ND_ + c];
        #pragma unroll
        for (int rr = 0; rr < 4; rr++) {
            const float4 x = *reinterpret_cast<const float4*>(&xs[rr][k]);
            acc[rr] += x.x * w0 + x.y * w1 + x.z * w2 + x.w * w3;
        }
    }
    const float bias = (m == 0) ? (bnq[c] + beq[c])
                     : (m == 1) ? (bnk[c] + bek[c])
                                : (bnv[c] + bev[c]);
    const int h = c >> 5, d = c & 31;
    #pragma unroll
    for (int rr = 0; rr < 4; rr++) {
        const int g  = g0 + rr;
        const int bb = g >> 9, ii = g & (N_ - 1);
        const int bh = bb * NH_ + h;
        const float y = acc[rr] + bias;
        if (m == 0) {
            Qh[((size_t)bh * N_ + ii) * DH_ + d] = y;
        } else {
            const int set = ((m == 1) ? 0 : 2) + (d >> 4);
            const size_t idx = (((size_t)bh * 32 + (ii >> 4)) * 4 + set) * 256
                             + (size_t)((((d >> 2) & 3) * 16 + (ii & 15)) * 4 + (d & 3));
            KVp[idx] = y;
        }
    }
}

// ---------------- main fused kernel: one block per (b, 4 i-rows), 8 waves = 8 heads.
// FOUR query rows per block: K/V fragment loads amortize 4x, 4 independent
// dependence chains per wave. K/V prefetch is 2-deep (two named register sets)
// so every consume-wait is vmcnt(>=4) and never drains the HBM edge-staging
// loads. Edge staging is split: rows 0-1 issued at chunk start / LDS-written
// mid-chunk; rows 2-3 issued mid-chunk / written at chunk end.
__global__ __launch_bounds__(512, 2) void attn_kernel(
    const float* __restrict__ edge,
    const float* __restrict__ Qh, const float* __restrict__ KVp,
    const unsigned short* __restrict__ W16, float* __restrict__ out)
{
    __shared__ unsigned short lds_[2][4][64 * 72];   // [buf][i-row][64 rows * 72]

    const int tid  = threadIdx.x;
    const int lane = tid & 63;
    const int h    = tid >> 6;       // wave id == head
    const int q4   = lane >> 4;
    const int l15  = lane & 15;
    const int blk  = blockIdx.x;     // 0..255
    const int b    = blk >> 7;
    const int i0   = (blk & 127) * 4;
    const int bh   = b * NH_ + h;

    // W A-operand frags: A[m=l15][k=q4*8+kk]; wf[m][half][ks]
    bf16x8 wf[3][2][2];
    #pragma unroll
    for (int m = 0; m < 3; m++)
        #pragma unroll
        for (int hf = 0; hf < 2; hf++)
            #pragma unroll
            for (int ks = 0; ks < 2; ks++) {
                const u32x4* p = reinterpret_cast<const u32x4*>(
                    W16 + m * (ND_ * ED_) + (h * DH_ + hf * 16 + l15) * ED_ + ks * 32 + q4 * 8);
                wf[m][hf][ks] = __builtin_bit_cast(bf16x8, *p);
            }

    // Q C-init (row d = q4*4+r, broadcast over j=l15), for all 4 i rows
    f32x4 Cq[4][2];
    {
        const float* Qrow = Qh + ((size_t)bh * N_ + i0) * DH_;
        #pragma unroll
        for (int ii = 0; ii < 4; ii++) {
            Cq[ii][0] = *reinterpret_cast<const f32x4*>(Qrow + ii * DH_ + q4 * 4);
            Cq[ii][1] = *reinterpret_cast<const f32x4*>(Qrow + ii * DH_ + 16 + q4 * 4);
        }
    }

    // lane-linear K/V fragment base: per jg, sets at +0,+64,+128,+192 (f32x4)
    const f32x4* kvb = reinterpret_cast<const f32x4*>(KVp + (size_t)bh * 32 * 1024) + lane;

    const float* eb[4];
    #pragma unroll
    for (int ii = 0; ii < 4; ii++)
        eb[ii] = edge + (size_t)(b * N_ + i0 + ii) * N_ * ED_;

    float l_acc[4] = {0.f, 0.f, 0.f, 0.f};
    f32x4 o0[4], o1[4];
    #pragma unroll
    for (int ii = 0; ii < 4; ii++) { o0[ii] = (f32x4){0.f,0.f,0.f,0.f}; o1[ii] = (f32x4){0.f,0.f,0.f,0.f}; }
    const float scale = 0.17677669529663687f;   // 1/sqrt(32)

#define KV_PREFETCH(KA0, KA1, VA0, VA1, JG) do {                               \
        const f32x4* pp_ = kvb + (size_t)((JG) & 31) * 256;                    \
        KA0 = pp_[0]; KA1 = pp_[64]; VA0 = pp_[128]; VA1 = pp_[192];           \
    } while (0)

#define ISSUE_HALF(gA, gB, gC, gD, H, CN) do {                                 \
        const float4* p0_ = reinterpret_cast<const float4*>(eb[(H)*2]     + (CN) * 4096); \
        const float4* p1_ = reinterpret_cast<const float4*>(eb[(H)*2 + 1] + (CN) * 4096); \
        gA = p0_[tid]; gB = p0_[tid + 512]; gC = p1_[tid]; gD = p1_[tid + 512]; \
    } while (0)

#define WRITE_HALF(gA, gB, gC, gD, H, NB) do {                                 \
        unsigned short* b0_ = &lds_[NB][(H)*2][0];                             \
        unsigned short* b1_ = &lds_[NB][(H)*2 + 1][0];                         \
        { uint2 v_ = {pack_bf16(gA.x, gA.y), pack_bf16(gA.z, gA.w)};           \
          *reinterpret_cast<uint2*>(b0_ + (tid >> 4) * 72 + (tid & 15) * 4) = v_; } \
        { const int f_ = tid + 512;                                            \
          uint2 v_ = {pack_bf16(gB.x, gB.y), pack_bf16(gB.z, gB.w)};           \
          *reinterpret_cast<uint2*>(b0_ + (f_ >> 4) * 72 + (f_ & 15) * 4) = v_; } \
        { uint2 v_ = {pack_bf16(gC.x, gC.y), pack_bf16(gC.z, gC.w)};           \
          *reinterpret_cast<uint2*>(b1_ + (tid >> 4) * 72 + (tid & 15) * 4) = v_; } \
        { const int f_ = tid + 512;                                            \
          uint2 v_ = {pack_bf16(gD.x, gD.y), pack_bf16(gD.z, gD.w)};           \
          *reinterpret_cast<uint2*>(b1_ + (f_ >> 4) * 72 + (f_ & 15) * 4) = v_; } \
    } while (0)

#define DO_SUB(SI, KA0, KA1, VA0, VA1) do {                                    \
        const f32x4 Ck0 = KA0, Ck1 = KA1, Cv0 = VA0, Cv1 = VA1;                \
        KV_PREFETCH(KA0, KA1, VA0, VA1, ch * 4 + (SI) + 2);                    \
        const unsigned short* cbase_ = &lds_[ch & 1][0][0];                    \
        _Pragma("unroll")                                                      \
        for (int ii = 0; ii < 4; ii++) {                                       \
            const unsigned short* ar_ = cbase_ + ii * (64 * 72)                \
                                      + ((SI) * 16 + l15) * 72 + q4 * 8;       \
            const bf16x8 aA = __builtin_bit_cast(bf16x8, *reinterpret_cast<const u32x4*>(ar_));      \
            const bf16x8 aB = __builtin_bit_cast(bf16x8, *reinterpret_cast<const u32x4*>(ar_ + 32)); \
            __builtin_amdgcn_s_setprio(1);                                     \
            f32x4 eq0 = __builtin_amdgcn_mfma_f32_16x16x32_bf16(wf[0][0][0], aA, Cq[ii][0], 0, 0, 0); \
            f32x4 eq1 = __builtin_amdgcn_mfma_f32_16x16x32_bf16(wf[0][1][0], aA, Cq[ii][1], 0, 0, 0); \
            f32x4 ek0 = __builtin_amdgcn_mfma_f32_16x16x32_bf16(wf[1][0][0], aA, Ck0, 0, 0, 0);       \
            f32x4 ek1 = __builtin_amdgcn_mfma_f32_16x16x32_bf16(wf[1][1][0], aA, Ck1, 0, 0, 0);       \
            f32x4 ev0 = __builtin_amdgcn_mfma_f32_16x16x32_bf16(wf[2][0][0], aA, Cv0, 0, 0, 0);       \
            f32x4 ev1 = __builtin_amdgcn_mfma_f32_16x16x32_bf16(wf[2][1][0], aA, Cv1, 0, 0, 0);       \
            eq0 = __builtin_amdgcn_mfma_f32_16x16x32_bf16(wf[0][0][1], aB, eq0, 0, 0, 0);             \
            eq1 = __builtin_amdgcn_mfma_f32_16x16x32_bf16(wf[0][1][1], aB, eq1, 0, 0, 0);             \
            ek0 = __builtin_amdgcn_mfma_f32_16x16x32_bf16(wf[1][0][1], aB, ek0, 0, 0, 0);             \
            ek1 = __builtin_amdgcn_mfma_f32_16x16x32_bf16(wf[1][1][1], aB, ek1, 0, 0, 0);             \
            ev0 = __builtin_amdgcn_mfma_f32_16x16x32_bf16(wf[2][0][1], aB, ev0, 0, 0, 0);             \
            ev1 = __builtin_amdgcn_mfma_f32_16x16x32_bf16(wf[2][1][1], aB, ev1, 0, 0, 0);             \
            __builtin_amdgcn_s_setprio(0);                                     \
            float ta = eq0[0]*ek0[0] + eq0[1]*ek0[1];                          \
            float tb = eq0[2]*ek0[2] + eq0[3]*ek0[3];                          \
            float tc = eq1[0]*ek1[0] + eq1[1]*ek1[1];                          \
            float td = eq1[2]*ek1[2] + eq1[3]*ek1[3];                          \
            float t = (ta + tb) + (tc + td);                                   \
            t += __shfl_xor(t, 16, 64);                                        \
            t += __shfl_xor(t, 32, 64);                                        \
            const float p = __expf(fmaf(t, scale, -4.f));                      \
            l_acc[ii] += p;                                                    \
            o0[ii] += ev0 * p;                                                 \
            o1[ii] += ev1 * p;                                                 \
        }                                                                      \
    } while (0)

    // ---- prologue: stage chunk 0 (all 4 rows), prefetch KV jg=0,1
    float4 ga0, ga1, ga2, ga3, gb0, gb1, gb2, gb3;
    ISSUE_HALF(ga0, ga1, ga2, ga3, 0, 0);
    ISSUE_HALF(gb0, gb1, gb2, gb3, 1, 0);
    WRITE_HALF(ga0, ga1, ga2, ga3, 0, 0);
    WRITE_HALF(gb0, gb1, gb2, gb3, 1, 0);
    f32x4 k0a, k0b, v0a, v0b, k1a, k1b, v1a, v1b;
    KV_PREFETCH(k0a, k0b, v0a, v0b, 0);
    KV_PREFETCH(k1a, k1b, v1a, v1b, 1);
    __syncthreads();

    #pragma unroll 1
    for (int ch = 0; ch < 8; ch++) {
        if (ch < 7) ISSUE_HALF(ga0, ga1, ga2, ga3, 0, ch + 1);
        DO_SUB(0, k0a, k0b, v0a, v0b);
        DO_SUB(1, k1a, k1b, v1a, v1b);
        if (ch < 7) {
            WRITE_HALF(ga0, ga1, ga2, ga3, 0, (ch + 1) & 1);
            ISSUE_HALF(gb0, gb1, gb2, gb3, 1, ch + 1);
        }
        DO_SUB(2, k0a, k0b, v0a, v0b);
        DO_SUB(3, k1a, k1b, v1a, v1b);
        if (ch < 7) WRITE_HALF(gb0, gb1, gb2, gb3, 1, (ch + 1) & 1);
        __syncthreads();
    }

    // final reductions over the 16 j-classes (l15); masks 1..8 stay in-quad
    #pragma unroll
    for (int mask = 1; mask <= 8; mask <<= 1) {
        #pragma unroll
        for (int ii = 0; ii < 4; ii++) {
            l_acc[ii] += __shfl_xor(l_acc[ii], mask, 64);
            #pragma unroll
            for (int r = 0; r < 4; r++) {
                o0[ii][r] += __shfl_xor(o0[ii][r], mask, 64);
                o1[ii][r] += __shfl_xor(o1[ii][r], mask, 64);
            }
        }
    }
    if (l15 == 0) {
        #pragma unroll
        for (int ii = 0; ii < 4; ii++) {
            const float inv = 1.f / l_acc[ii];
            float* orow = out + ((size_t)(b * N_ + i0 + ii)) * ND_ + h * DH_ + q4 * 4;
            float4 va = {o0[ii][0] * inv, o0[ii][1] * inv, o0[ii][2] * inv, o0[ii][3] * inv};
            float4 vb = {o1[ii][0] * inv, o1[ii][1] * inv, o1[ii][2] * inv, o1[ii][3] * inv};
            *reinterpret_cast<float4*>(orow)      = va;
            *reinterpret_cast<float4*>(orow + 16) = vb;
        }
    }
#undef KV_PREFETCH
#undef ISSUE_HALF
#undef WRITE_HALF
#undef DO_SUB
}

extern "C" void kernel_launch(void* const* d_in, const int* in_sizes, int n_in,
                              void* d_out, int out_size, void* d_ws, size_t ws_size,
                              hipStream_t stream) {
    const float* node = (const float*)d_in[0];
    const float* edge = (const float*)d_in[1];
    const float* Wnq  = (const float*)d_in[2];
    const float* bnq  = (const float*)d_in[3];
    const float* Wnk  = (const float*)d_in[4];
    const float* bnk  = (const float*)d_in[5];
    const float* Wnv  = (const float*)d_in[6];
    const float* bnv  = (const float*)d_in[7];
    const float* Weq  = (const float*)d_in[8];
    const float* beq  = (const float*)d_in[9];
    const float* Wek  = (const float*)d_in[10];
    const float* bek  = (const float*)d_in[11];
    const float* Wev  = (const float*)d_in[12];
    const float* bev  = (const float*)d_in[13];

    char* ws = (char*)d_ws;
    unsigned short* W16 = (unsigned short*)ws;              // 96 KB (pad to 128 KB)
    float* Wt  = (float*)(ws + 131072);                     // 768 KB
    float* Qh  = (float*)(ws + 131072 + 786432);            // 1 MB
    float* KVp = (float*)(ws + 131072 + 786432 + 1048576);  // 2 MB
    float* out = (float*)d_out;

    cvt_w_kernel<<<192, 256, 0, stream>>>(Weq, Wek, Wev, W16);
    trans_w_kernel<<<192, 256, 0, stream>>>(Wnq, Wnk, Wnv, Wt);
    qkv_kernel<<<768, 256, 0, stream>>>(node, Wt, bnq, bnk, bnv, beq, bek, bev, Qh, KVp);
    attn_kernel<<<256, 512, 0, stream>>>(edge, Qh, KVp, W16, out);
}

// Round 3
// 438.665 us; speedup vs baseline: 1.0632x; 1.0632x over previous
//
#include <hip/hip_runtime.h>

typedef __bf16 bf16x8 __attribute__((ext_vector_type(8)));
typedef float  f32x4  __attribute__((ext_vector_type(4)));
typedef unsigned int u32x4 __attribute__((ext_vector_type(4)));

#define B_   2
#define N_   512
#define ND_  256
#define ED_  64
#define NH_  8
#define DH_  32

static __device__ __forceinline__ unsigned pack_bf16(float a, float b) {
    unsigned short ua = __builtin_bit_cast(unsigned short, (__bf16)a);
    unsigned short ub = __builtin_bit_cast(unsigned short, (__bf16)b);
    return (unsigned)ua | ((unsigned)ub << 16);
}

// ---------------- prep kernel 1: edge-weight fp32 -> bf16 (row-major [256][64])
__global__ __launch_bounds__(256) void cvt_w_kernel(
    const float* __restrict__ wq, const float* __restrict__ wk,
    const float* __restrict__ wv, unsigned short* __restrict__ w16)
{
    int id = blockIdx.x * 256 + threadIdx.x;          // 0..49151
    const float* src = (id < 16384) ? wq : (id < 32768 ? wk : wv);
    int idx = id & 16383;
    w16[id] = __builtin_bit_cast(unsigned short, (__bf16)src[idx]);
}

// ---------------- prep kernel 1b: transpose node weights -> Wt[m][k][c] fp32
__global__ __launch_bounds__(256) void trans_w_kernel(
    const float* __restrict__ Wq, const float* __restrict__ Wk,
    const float* __restrict__ Wv, float* __restrict__ Wt)
{
    __shared__ float t[32][33];
    const int bx = blockIdx.x;        // 0..191 = 3 mats * 64 tiles
    const int m  = bx >> 6;
    const int t6 = bx & 63;
    const int cb = (t6 >> 3) << 5;    // c-block
    const int kb = (t6 & 7) << 5;     // k-block
    const float* W = (m == 0) ? Wq : (m == 1 ? Wk : Wv);
    const int tx = threadIdx.x & 31, ty = threadIdx.x >> 5;   // 32 x 8
    #pragma unroll
    for (int s = 0; s < 4; s++)
        t[ty + 8 * s][tx] = W[(size_t)(cb + ty + 8 * s) * ND_ + kb + tx];
    __syncthreads();
    float* dst = Wt + (size_t)m * ND_ * ND_;
    #pragma unroll
    for (int s = 0; s < 4; s++)
        dst[(size_t)(kb + ty + 8 * s) * ND_ + cb + tx] = t[tx][ty + 8 * s];
}

// ------- prep kernel 2: node projections with coalesced (transposed) weights.
// Q -> row-major head-split Qh[bh][i][32].
// K,V -> KVp in MFMA C-fragment order so attn loads are lane-linear:
//   KVp float idx = ((bh*32 + j/16)*4 + set)*256 + (((d>>2)&3)*16 + (j&15))*4 + (d&3)
//   set: 0,1 = K halves (d<16 / d>=16), 2,3 = V halves.
__global__ __launch_bounds__(256) void qkv_kernel(
    const float* __restrict__ node, const float* __restrict__ Wt,
    const float* __restrict__ bnq, const float* __restrict__ bnk,
    const float* __restrict__ bnv, const float* __restrict__ beq,
    const float* __restrict__ bek, const float* __restrict__ bev,
    float* __restrict__ Qh, float* __restrict__ KVp)
{
    __shared__ float xs[4][ND_];
    const int c   = threadIdx.x;
    const int m   = blockIdx.x >> 8;       // 0=Q 1=K 2=V
    const int grp = blockIdx.x & 255;
    const int g0  = grp * 4;
    {
        const int r = c >> 6, col4 = (c & 63) * 4;
        const float4 v = *reinterpret_cast<const float4*>(node + (size_t)(g0 + r) * ND_ + col4);
        *reinterpret_cast<float4*>(&xs[r][col4]) = v;
    }
    __syncthreads();

    const float* Wm = Wt + (size_t)m * ND_ * ND_;
    float acc[4] = {0.f, 0.f, 0.f, 0.f};
    for (int k = 0; k < ND_; k += 4) {
        const float w0 = Wm[(size_t)(k + 0) * ND_ + c];
        const float w1 = Wm[(size_t)(k + 1) * ND_ + c];
        const float w2 = Wm[(size_t)(k + 2) * ND_ + c];
        const float w3 = Wm[(size_t)(k + 3) * ND_ + c];
        #pragma unroll
        for (int rr = 0; rr < 4; rr++) {
            const float4 x = *reinterpret_cast<const float4*>(&xs[rr][k]);
            acc[rr] += x.x * w0 + x.y * w1 + x.z * w2 + x.w * w3;
        }
    }
    const float bias = (m == 0) ? (bnq[c] + beq[c])
                     : (m == 1) ? (bnk[c] + bek[c])
                                : (bnv[c] + bev[c]);
    const int h = c >> 5, d = c & 31;
    #pragma unroll
    for (int rr = 0; rr < 4; rr++) {
        const int g  = g0 + rr;
        const int bb = g >> 9, ii = g & (N_ - 1);
        const int bh = bb * NH_ + h;
        const float y = acc[rr] + bias;
        if (m == 0) {
            Qh[((size_t)bh * N_ + ii) * DH_ + d] = y;
        } else {
            const int set = ((m == 1) ? 0 : 2) + (d >> 4);
            const size_t idx = (((size_t)bh * 32 + (ii >> 4)) * 4 + set) * 256
                             + (size_t)((((d >> 2) & 3) * 16 + (ii & 15)) * 4 + (d & 3));
            KVp[idx] = y;
        }
    }
}

// ---------------- main fused kernel: one block per (b, 4 i-rows), 8 waves = 8 heads.
// Round-2 pipeline (4 rows, 2-deep KV prefetch, split staging) with the spill
// fixed: __launch_bounds__(512,1) gives the allocator the full 256-VGPR budget
// (8-wave block => 2 waves/SIMD co-resident => 256 is the hard cap anyway),
// and DO_SUB consumes the named KV set directly as MFMA C-operands (no copies).
// vmcnt ordering invariant: every KV consume targets a load issued >=2 subs
// earlier AND older than any in-flight HBM staging load; every staging write
// waits on loads with >=2 subs of compute cover.
__global__ __launch_bounds__(512, 1) void attn_kernel(
    const float* __restrict__ edge,
    const float* __restrict__ Qh, const float* __restrict__ KVp,
    const unsigned short* __restrict__ W16, float* __restrict__ out)
{
    __shared__ unsigned short lds_[2][4][64 * 72];   // [buf][i-row][64 rows * 72]

    const int tid  = threadIdx.x;
    const int lane = tid & 63;
    const int h    = tid >> 6;       // wave id == head
    const int q4   = lane >> 4;
    const int l15  = lane & 15;
    const int blk  = blockIdx.x;     // 0..255
    const int b    = blk >> 7;
    const int i0   = (blk & 127) * 4;
    const int bh   = b * NH_ + h;

    // W A-operand frags: A[m=l15][k=q4*8+kk]; wf[m][half][ks]
    bf16x8 wf[3][2][2];
    #pragma unroll
    for (int m = 0; m < 3; m++)
        #pragma unroll
        for (int hf = 0; hf < 2; hf++)
            #pragma unroll
            for (int ks = 0; ks < 2; ks++) {
                const u32x4* p = reinterpret_cast<const u32x4*>(
                    W16 + m * (ND_ * ED_) + (h * DH_ + hf * 16 + l15) * ED_ + ks * 32 + q4 * 8);
                wf[m][hf][ks] = __builtin_bit_cast(bf16x8, *p);
            }

    // Q C-init (row d = q4*4+r, broadcast over j=l15), for all 4 i rows
    f32x4 Cq[4][2];
    {
        const float* Qrow = Qh + ((size_t)bh * N_ + i0) * DH_;
        #pragma unroll
        for (int ii = 0; ii < 4; ii++) {
            Cq[ii][0] = *reinterpret_cast<const f32x4*>(Qrow + ii * DH_ + q4 * 4);
            Cq[ii][1] = *reinterpret_cast<const f32x4*>(Qrow + ii * DH_ + 16 + q4 * 4);
        }
    }

    // lane-linear K/V fragment base: per jg, sets at +0,+64,+128,+192 (f32x4)
    const f32x4* kvb = reinterpret_cast<const f32x4*>(KVp + (size_t)bh * 32 * 1024) + lane;

    const float* eb0 = edge + (size_t)(b * N_ + i0) * N_ * ED_;   // row stride N_*ED_

    float l_acc[4] = {0.f, 0.f, 0.f, 0.f};
    f32x4 o0[4], o1[4];
    #pragma unroll
    for (int ii = 0; ii < 4; ii++) { o0[ii] = (f32x4){0.f,0.f,0.f,0.f}; o1[ii] = (f32x4){0.f,0.f,0.f,0.f}; }
    const float scale = 0.17677669529663687f;   // 1/sqrt(32)

#define KV_PREFETCH(KA0, KA1, VA0, VA1, JG) do {                               \
        const f32x4* pp_ = kvb + (size_t)((JG) & 31) * 256;                    \
        KA0 = pp_[0]; KA1 = pp_[64]; VA0 = pp_[128]; VA1 = pp_[192];           \
    } while (0)

#define ISSUE_HALF(gA, gB, gC, gD, H, CN) do {                                 \
        const float4* p0_ = reinterpret_cast<const float4*>(eb0 + (size_t)((H)*2)     * (N_*ED_) + (CN) * 4096); \
        const float4* p1_ = reinterpret_cast<const float4*>(eb0 + (size_t)((H)*2 + 1) * (N_*ED_) + (CN) * 4096); \
        gA = p0_[tid]; gB = p0_[tid + 512]; gC = p1_[tid]; gD = p1_[tid + 512]; \
    } while (0)

#define WRITE_HALF(gA, gB, gC, gD, H, NB) do {                                 \
        unsigned short* b0_ = &lds_[NB][(H)*2][0];                             \
        unsigned short* b1_ = &lds_[NB][(H)*2 + 1][0];                         \
        { uint2 v_ = {pack_bf16(gA.x, gA.y), pack_bf16(gA.z, gA.w)};           \
          *reinterpret_cast<uint2*>(b0_ + (tid >> 4) * 72 + (tid & 15) * 4) = v_; } \
        { const int f_ = tid + 512;                                            \
          uint2 v_ = {pack_bf16(gB.x, gB.y), pack_bf16(gB.z, gB.w)};           \
          *reinterpret_cast<uint2*>(b0_ + (f_ >> 4) * 72 + (f_ & 15) * 4) = v_; } \
        { uint2 v_ = {pack_bf16(gC.x, gC.y), pack_bf16(gC.z, gC.w)};           \
          *reinterpret_cast<uint2*>(b1_ + (tid >> 4) * 72 + (tid & 15) * 4) = v_; } \
        { const int f_ = tid + 512;                                            \
          uint2 v_ = {pack_bf16(gD.x, gD.y), pack_bf16(gD.z, gD.w)};           \
          *reinterpret_cast<uint2*>(b1_ + (f_ >> 4) * 72 + (f_ & 15) * 4) = v_; } \
    } while (0)

// Consumes the named KV set directly as MFMA C-operands (no copies), then
// refills the same set for jg+2 AFTER its last C-use (keeps one set live).
#define DO_SUB(SI, KA0, KA1, VA0, VA1) do {                                    \
        const unsigned short* cbase_ = &lds_[ch & 1][0][0];                    \
        _Pragma("unroll")                                                      \
        for (int ii = 0; ii < 4; ii++) {                                       \
            const unsigned short* ar_ = cbase_ + ii * (64 * 72)                \
                                      + ((SI) * 16 + l15) * 72 + q4 * 8;       \
            const bf16x8 aA = __builtin_bit_cast(bf16x8, *reinterpret_cast<const u32x4*>(ar_));      \
            const bf16x8 aB = __builtin_bit_cast(bf16x8, *reinterpret_cast<const u32x4*>(ar_ + 32)); \
            __builtin_amdgcn_s_setprio(1);                                     \
            f32x4 eq0 = __builtin_amdgcn_mfma_f32_16x16x32_bf16(wf[0][0][0], aA, Cq[ii][0], 0, 0, 0); \
            f32x4 eq1 = __builtin_amdgcn_mfma_f32_16x16x32_bf16(wf[0][1][0], aA, Cq[ii][1], 0, 0, 0); \
            f32x4 ek0 = __builtin_amdgcn_mfma_f32_16x16x32_bf16(wf[1][0][0], aA, KA0, 0, 0, 0);       \
            f32x4 ek1 = __builtin_amdgcn_mfma_f32_16x16x32_bf16(wf[1][1][0], aA, KA1, 0, 0, 0);       \
            f32x4 ev0 = __builtin_amdgcn_mfma_f32_16x16x32_bf16(wf[2][0][0], aA, VA0, 0, 0, 0);       \
            f32x4 ev1 = __builtin_amdgcn_mfma_f32_16x16x32_bf16(wf[2][1][0], aA, VA1, 0, 0, 0);       \
            eq0 = __builtin_amdgcn_mfma_f32_16x16x32_bf16(wf[0][0][1], aB, eq0, 0, 0, 0);             \
            eq1 = __builtin_amdgcn_mfma_f32_16x16x32_bf16(wf[0][1][1], aB, eq1, 0, 0, 0);             \
            ek0 = __builtin_amdgcn_mfma_f32_16x16x32_bf16(wf[1][0][1], aB, ek0, 0, 0, 0);             \
            ek1 = __builtin_amdgcn_mfma_f32_16x16x32_bf16(wf[1][1][1], aB, ek1, 0, 0, 0);             \
            ev0 = __builtin_amdgcn_mfma_f32_16x16x32_bf16(wf[2][0][1], aB, ev0, 0, 0, 0);             \
            ev1 = __builtin_amdgcn_mfma_f32_16x16x32_bf16(wf[2][1][1], aB, ev1, 0, 0, 0);             \
            __builtin_amdgcn_s_setprio(0);                                     \
            float ta = eq0[0]*ek0[0] + eq0[1]*ek0[1];                          \
            float tb = eq0[2]*ek0[2] + eq0[3]*ek0[3];                          \
            float tc = eq1[0]*ek1[0] + eq1[1]*ek1[1];                          \
            float td = eq1[2]*ek1[2] + eq1[3]*ek1[3];                          \
            float t = (ta + tb) + (tc + td);                                   \
            t += __shfl_xor(t, 16, 64);                                        \
            t += __shfl_xor(t, 32, 64);                                        \
            const float p = __expf(fmaf(t, scale, -4.f));                      \
            l_acc[ii] += p;                                                    \
            o0[ii] += ev0 * p;                                                 \
            o1[ii] += ev1 * p;                                                 \
        }                                                                      \
        KV_PREFETCH(KA0, KA1, VA0, VA1, ch * 4 + (SI) + 2);                    \
    } while (0)

    // ---- prologue: KV jg=0,1 first (oldest in queue), then stage chunk 0
    f32x4 k0a, k0b, v0a, v0b, k1a, k1b, v1a, v1b;
    KV_PREFETCH(k0a, k0b, v0a, v0b, 0);
    KV_PREFETCH(k1a, k1b, v1a, v1b, 1);
    float4 ga0, ga1, ga2, ga3, gb0, gb1, gb2, gb3;
    ISSUE_HALF(ga0, ga1, ga2, ga3, 0, 0);
    ISSUE_HALF(gb0, gb1, gb2, gb3, 1, 0);
    WRITE_HALF(ga0, ga1, ga2, ga3, 0, 0);
    WRITE_HALF(gb0, gb1, gb2, gb3, 1, 0);
    __syncthreads();

    #pragma unroll 1
    for (int ch = 0; ch < 8; ch++) {
        if (ch < 7) ISSUE_HALF(ga0, ga1, ga2, ga3, 0, ch + 1);
        DO_SUB(0, k0a, k0b, v0a, v0b);
        DO_SUB(1, k1a, k1b, v1a, v1b);
        if (ch < 7) {
            WRITE_HALF(ga0, ga1, ga2, ga3, 0, (ch + 1) & 1);
            ISSUE_HALF(gb0, gb1, gb2, gb3, 1, ch + 1);
        }
        DO_SUB(2, k0a, k0b, v0a, v0b);
        DO_SUB(3, k1a, k1b, v1a, v1b);
        if (ch < 7) WRITE_HALF(gb0, gb1, gb2, gb3, 1, (ch + 1) & 1);
        __syncthreads();
    }

    // final reductions over the 16 j-classes (l15); masks 1..8 stay in-quad
    #pragma unroll
    for (int mask = 1; mask <= 8; mask <<= 1) {
        #pragma unroll
        for (int ii = 0; ii < 4; ii++) {
            l_acc[ii] += __shfl_xor(l_acc[ii], mask, 64);
            #pragma unroll
            for (int r = 0; r < 4; r++) {
                o0[ii][r] += __shfl_xor(o0[ii][r], mask, 64);
                o1[ii][r] += __shfl_xor(o1[ii][r], mask, 64);
            }
        }
    }
    if (l15 == 0) {
        #pragma unroll
        for (int ii = 0; ii < 4; ii++) {
            const float inv = 1.f / l_acc[ii];
            float* orow = out + ((size_t)(b * N_ + i0 + ii)) * ND_ + h * DH_ + q4 * 4;
            float4 va = {o0[ii][0] * inv, o0[ii][1] * inv, o0[ii][2] * inv, o0[ii][3] * inv};
            float4 vb = {o1[ii][0] * inv, o1[ii][1] * inv, o1[ii][2] * inv, o1[ii][3] * inv};
            *reinterpret_cast<float4*>(orow)      = va;
            *reinterpret_cast<float4*>(orow + 16) = vb;
        }
    }
#undef KV_PREFETCH
#undef ISSUE_HALF
#undef WRITE_HALF
#undef DO_SUB
}

extern "C" void kernel_launch(void* const* d_in, const int* in_sizes, int n_in,
                              void* d_out, int out_size, void* d_ws, size_t ws_size,
                              hipStream_t stream) {
    const float* node = (const float*)d_in[0];
    const float* edge = (const float*)d_in[1];
    const float* Wnq  = (const float*)d_in[2];
    const float* bnq  = (const float*)d_in[3];
    const float* Wnk  = (const float*)d_in[4];
    const float* bnk  = (const float*)d_in[5];
    const float* Wnv  = (const float*)d_in[6];
    const float* bnv  = (const float*)d_in[7];
    const float* Weq  = (const float*)d_in[8];
    const float* beq  = (const float*)d_in[9];
    const float* Wek  = (const float*)d_in[10];
    const float* bek  = (const float*)d_in[11];
    const float* Wev  = (const float*)d_in[12];
    const float* bev  = (const float*)d_in[13];

    char* ws = (char*)d_ws;
    unsigned short* W16 = (unsigned short*)ws;              // 96 KB (pad to 128 KB)
    float* Wt  = (float*)(ws + 131072);                     // 768 KB
    float* Qh  = (float*)(ws + 131072 + 786432);            // 1 MB
    float* KVp = (float*)(ws + 131072 + 786432 + 1048576);  // 2 MB
    float* out = (float*)d_out;

    cvt_w_kernel<<<192, 256, 0, stream>>>(Weq, Wek, Wev, W16);
    trans_w_kernel<<<192, 256, 0, stream>>>(Wnq, Wnk, Wnv, Wt);
    qkv_kernel<<<768, 256, 0, stream>>>(node, Wt, bnq, bnk, bnv, beq, bek, bev, Qh, KVp);
    attn_kernel<<<256, 512, 0, stream>>>(edge, Qh, KVp, W16, out);
}